// Round 6
// baseline (258.022 us; speedup 1.0000x reference)
//
#include <hip/hip_runtime.h>
#include <stdint.h>

#define HH 128
#define WW 128
#define NPIX 16384
#define BTN 32
#define CCH 64
#define MPAR 256
#define SENT 16384
#define NSTEPS 40
#define PXW 128
#define NWAVE (BTN * NPIX / PXW)   // 4096 chunk-waves, 128 per image

// ---------------- Kernel A: 4-direction edge masks (LDS-tiled, early-out) ----------------
// bit0 E(0,1), bit1 SW(1,-1), bit2 S(1,0), bit3 SE(1,1)
// Edge condition: aff>0.5 <=> dist<1 <=> s+1e-12 < 1 (monotone transforms; no sqrt/div).
// Also zeroes acc+cnt (atomic-residue accumulators) for the downstream aggregation.
#define ETX 32
#define ETY 8
__global__ __launch_bounds__(256) void edge_kernel(const float* __restrict__ feat,
                                                   unsigned char* __restrict__ mask4,
                                                   float4* __restrict__ accz,
                                                   float4* __restrict__ cntz) {
  __shared__ float lds[8][308];           // [channel][staged pixel], 306 used
  int blk = blockIdx.x;                   // 2048 blocks
  int tid = threadIdx.x;

  // zero acc: 262144 float4 over 2048 blocks = 128/block; cnt: 2048 float4 = 1/block
  if (tid < 128) accz[blk * 128 + tid] = make_float4(0.f, 0.f, 0.f, 0.f);
  else if (tid == 128) cntz[blk] = make_float4(0.f, 0.f, 0.f, 0.f);

  int b = blk >> 6;
  int t = blk & 63;                       // 16 tile-rows x 4 tile-cols
  int ty0 = (t >> 2) * ETY;
  int tx0 = (t & 3) * ETX;
  const float* fb = feat + ((size_t)b << 20);   // b * 16384 * 64

  for (int sp = tid; sp < 306; sp += 256) {
    int gy = ty0 + sp / 34;
    int gx = tx0 - 1 + sp % 34;
    if (gy < HH && (unsigned)gx < (unsigned)WW) {
      const float* pp = fb + (((size_t)(gy << 7) + gx) << 6);
      float4 v0 = *(const float4*)pp;
      float4 v1 = *(const float4*)(pp + 4);
      lds[0][sp] = v0.x; lds[1][sp] = v0.y; lds[2][sp] = v0.z; lds[3][sp] = v0.w;
      lds[4][sp] = v1.x; lds[5][sp] = v1.y; lds[6][sp] = v1.z; lds[7][sp] = v1.w;
    } else {
#pragma unroll
      for (int c = 0; c < 8; ++c) lds[c][sp] = 1e6f;
    }
  }
  __syncthreads();

  int tx = tid & 31, ty = tid >> 5;
  int idx = ty * 34 + tx + 1;
  int gx = tx0 + tx, gy = ty0 + ty;

  float own[8];
#pragma unroll
  for (int c = 0; c < 8; ++c) own[c] = lds[c][idx];
  float a0 = 0.f, a1 = 0.f, a2 = 0.f, a3 = 0.f;
#pragma unroll
  for (int c = 0; c < 8; ++c) {
    float o = own[c];
    float d0 = o - lds[c][idx + 1];     // E
    float d1 = o - lds[c][idx + 33];    // SW
    float d2 = o - lds[c][idx + 34];    // S
    float d3 = o - lds[c][idx + 35];    // SE
    a0 += d0 * d0; a1 += d1 * d1; a2 += d2 * d2; a3 += d3 * d3;
  }

  bool vS = (gy + 1) < HH;
  float acc[4] = {a0, a1, a2, a3};
  bool val[4] = {(gx + 1) < WW, vS && gx >= 1, vS, vS && (gx + 1) < WW};
  const int offp[4] = {1, 127, 128, 129};
  const float* fp = fb + (((size_t)(gy << 7) + gx) << 6);
  unsigned m = 0;
#pragma unroll
  for (int j = 0; j < 4; ++j) {
    if (val[j]) {
      float s = acc[j];
      if (s < 1.0f) {                    // rare: finish channels 8..63 exactly
        const float* np_ = fp + ((size_t)offp[j] << 6);
        for (int c = 8; c < 64; ++c) {
          float d = fp[c] - np_[c];
          s += d * d;
        }
      }
      if (s + 1e-12f < 1.0f) m |= (1u << j);
    }
  }
  mask4[(b << 14) + (gy << 7) + gx] = (unsigned char)m;
}

// ---------------- Kernel B: propagation + relabel ----------------
// e8 bits: b0 NW, b1 N, b2 NE, b3 W, b4 E, b5 SW, b6 S, b7 SE
// Fast path: if the image has NO edges at all (image-wide OR of mask4 == 0), the exact
// result of propagate+relabel is seg[p] = min(p, 255) (identity labels, all present,
// rank = identity). Full path kept as the general-case fallback (exact for any input).
__global__ __launch_bounds__(1024) void prop_kernel(const unsigned char* __restrict__ mask4g,
                                                    unsigned char* __restrict__ segg) {
  __shared__ __align__(16) unsigned short lab[NPIX];   // 32 KB
  __shared__ __align__(16) unsigned char e8[NPIX];     // 16 KB
  __shared__ __align__(16) unsigned short rnk[NPIX];   // 32 KB
  __shared__ int flags[2];
  __shared__ int wsum[16];
  __shared__ int wexc[16];
  __shared__ int wany[16];
  int b = blockIdx.x;
  int tid = threadIdx.x;
  int lane = tid & 63, wid = tid >> 6;

  uint4 mv = ((const uint4*)(mask4g + ((size_t)b << 14)))[tid];
  ((uint4*)e8)[tid] = mv;
  unsigned anyv = mv.x | mv.y | mv.z | mv.w;
  unsigned long long bal = __ballot(anyv != 0);
  if (lane == 0) wany[wid] = (bal != 0ull) ? 1 : 0;
  __syncthreads();

  int tot = 0;
#pragma unroll
  for (int i = 0; i < 16; ++i) tot |= wany[i];   // LDS broadcast reads
  if (tot == 0) {
    // zero-edge closed form: seg[p] = min(p, 255); 16 coalesced bytes per thread
    uint4 w;
    if (tid < 16) {
      unsigned b0 = (unsigned)(tid * 16);
      w.x = b0 | ((b0 + 1) << 8) | ((b0 + 2) << 16) | ((b0 + 3) << 24);
      w.y = (b0 + 4) | ((b0 + 5) << 8) | ((b0 + 6) << 16) | ((b0 + 7) << 24);
      w.z = (b0 + 8) | ((b0 + 9) << 8) | ((b0 + 10) << 16) | ((b0 + 11) << 24);
      w.w = (b0 + 12) | ((b0 + 13) << 8) | ((b0 + 14) << 16) | ((b0 + 15) << 24);
    } else {
      w = make_uint4(~0u, ~0u, ~0u, ~0u);
    }
    ((uint4*)(segg + ((size_t)b << 14)))[tid] = w;
    return;
  }

  unsigned char tmp[16];
  {
    int base = tid * 16;
#pragma unroll
    for (int i = 0; i < 16; ++i) {
      int p = base + i;
      int y = p >> 7, x = p & (WW - 1);
      unsigned own = e8[p];
      unsigned nw = (y > 0 && x > 0) ? e8[p - 129] : 0;
      unsigned n_ = (y > 0) ? e8[p - 128] : 0;
      unsigned ne = (y > 0 && x < WW - 1) ? e8[p - 127] : 0;
      unsigned w_ = (x > 0) ? e8[p - 1] : 0;
      unsigned v = ((nw >> 3) & 1) | (((n_ >> 2) & 1) << 1) | (((ne >> 1) & 1) << 2) |
                   ((w_ & 1) << 3) | ((own & 1) << 4) | (((own >> 1) & 1) << 5) |
                   (((own >> 2) & 1) << 6) | (((own >> 3) & 1) << 7);
      tmp[i] = (unsigned char)v;
    }
  }
  __syncthreads();
  {
    int base = tid * 16;
#pragma unroll
    for (int i = 0; i < 16; ++i) e8[base + i] = tmp[i];
#pragma unroll
    for (int i = 0; i < 16; ++i) lab[base + i] = (unsigned short)(base + i);
  }
  if (tid == 0) { flags[0] = 0; flags[1] = 0; }
  __syncthreads();

  int x0 = (tid & 31) * 4, y0 = (tid >> 5) * 4;
  int cur[4][4], eb[4][4];
#pragma unroll
  for (int r = 0; r < 4; ++r)
#pragma unroll
    for (int c = 0; c < 4; ++c) {
      cur[r][c] = (y0 + r) * WW + x0 + c;
      eb[r][c] = e8[(y0 + r) * WW + x0 + c];
    }

  for (int it = 0; it < NSTEPS; ++it) {
    int top[6], bot[6], lft[4], rgt[4];
#pragma unroll
    for (int c = 0; c < 6; ++c) {
      top[c] = lab[(((y0 - 1) * WW) + x0 - 1 + c) & (NPIX - 1)];
      bot[c] = lab[(((y0 + 4) * WW) + x0 - 1 + c) & (NPIX - 1)];
    }
#pragma unroll
    for (int r = 0; r < 4; ++r) {
      lft[r] = lab[(((y0 + r) * WW) + x0 - 1) & (NPIX - 1)];
      rgt[r] = lab[(((y0 + r) * WW) + x0 + 4) & (NPIX - 1)];
    }
    int nl[4][4];
    bool ch = false;
#pragma unroll
    for (int r = 0; r < 4; ++r) {
#pragma unroll
      for (int c = 0; c < 4; ++c) {
        int m = cur[r][c];
        int e = eb[r][c];
        int v;
        v = (r > 0) ? ((c > 0) ? cur[r - 1][c - 1] : lft[r - 1]) : top[c];        // NW
        m = min(m, (e & 1) ? v : SENT);
        v = (r > 0) ? cur[r - 1][c] : top[c + 1];                                 // N
        m = min(m, (e & 2) ? v : SENT);
        v = (r > 0) ? ((c < 3) ? cur[r - 1][c + 1] : rgt[r - 1]) : top[c + 2];    // NE
        m = min(m, (e & 4) ? v : SENT);
        v = (c > 0) ? cur[r][c - 1] : lft[r];                                     // W
        m = min(m, (e & 8) ? v : SENT);
        v = (c < 3) ? cur[r][c + 1] : rgt[r];                                     // E
        m = min(m, (e & 16) ? v : SENT);
        v = (r < 3) ? ((c > 0) ? cur[r + 1][c - 1] : lft[r + 1]) : bot[c];        // SW
        m = min(m, (e & 32) ? v : SENT);
        v = (r < 3) ? cur[r + 1][c] : bot[c + 1];                                 // S
        m = min(m, (e & 64) ? v : SENT);
        v = (r < 3) ? ((c < 3) ? cur[r + 1][c + 1] : rgt[r + 1]) : bot[c + 2];    // SE
        m = min(m, (e & 128) ? v : SENT);
        nl[r][c] = m;
        ch |= (m != cur[r][c]);
      }
    }
    __syncthreads();
#pragma unroll
    for (int r = 0; r < 4; ++r) {
      unsigned lo = (unsigned)nl[r][0] | ((unsigned)nl[r][1] << 16);
      unsigned hi = (unsigned)nl[r][2] | ((unsigned)nl[r][3] << 16);
      *((uint2*)&lab[(y0 + r) * WW + x0]) = make_uint2(lo, hi);
    }
    if (ch) flags[it & 1] = 1;
    if (tid == 0) flags[(it + 1) & 1] = 0;
#pragma unroll
    for (int r = 0; r < 4; ++r)
#pragma unroll
      for (int c = 0; c < 4; ++c) cur[r][c] = nl[r][c];
    __syncthreads();
    if (!flags[it & 1]) break;   // converged: remaining iterations are identity (exact)
  }

  __syncthreads();
  ((uint4*)e8)[tid] = make_uint4(0u, 0u, 0u, 0u);
  __syncthreads();
#pragma unroll
  for (int i = 0; i < 16; ++i) {
    int p = tid + i * 1024;
    e8[lab[p]] = 1;
  }
  __syncthreads();
  int pres[16];
  int base = tid * 16;
#pragma unroll
  for (int i = 0; i < 16; ++i) pres[i] = e8[base + i];
  int s_local = 0;
#pragma unroll
  for (int i = 0; i < 16; ++i) s_local += pres[i];
  int inc = s_local;
#pragma unroll
  for (int off = 1; off < 64; off <<= 1) {
    int v = __shfl_up(inc, off, 64);
    if (lane >= off) inc += v;
  }
  if (lane == 63) wsum[wid] = inc;
  __syncthreads();
  if (wid == 0) {
    int tt = (lane < 16) ? wsum[lane] : 0;
    int winc = tt;
#pragma unroll
    for (int off = 1; off < 16; off <<= 1) {
      int v = __shfl_up(winc, off, 64);
      if (lane >= off) winc += v;
    }
    if (lane < 16) wexc[lane] = winc - tt;
  }
  __syncthreads();
  int run = wexc[wid] + (inc - s_local);
#pragma unroll
  for (int i = 0; i < 16; ++i) {
    run += pres[i];
    rnk[base + i] = (unsigned short)(run - 1);
  }
  __syncthreads();
  unsigned char* so = segg + ((size_t)b << 14);
#pragma unroll
  for (int i = 0; i < 16; ++i) {
    int p = tid + i * 1024;
    int sg = rnk[lab[p]];
    so[p] = (unsigned char)min(sg, 255);
  }
}

// ---------------- Kernel D: aggregation, ATOMIC-FREE hot path ----------------
// Evidence R3/R4/R5: agg time tracks total atomic-op count (address-independent), not
// loads or instructions. Hot path (uniform chunk): write the wave's private partial
// (seg, cnt, sum[64], sq[64]) to slot[gw] with PLAIN stores — zero atomics, zero
// contention. Mixed chunks (rare) keep the exact atomic run-flush into acc/cnt.
__global__ __launch_bounds__(256) void agg_kernel(const float* __restrict__ feat,
                                                  const unsigned char* __restrict__ segg,
                                                  float* __restrict__ acc,
                                                  float* __restrict__ cnt,
                                                  float* __restrict__ psum,
                                                  float* __restrict__ psq,
                                                  int* __restrict__ pseg,
                                                  float* __restrict__ pcnt) {
  int lane = threadIdx.x & 63;
  int wid = threadIdx.x >> 6;
  int gw = blockIdx.x * 4 + wid;          // 4096 waves, 128 per image
  int b = gw >> 7;
  int chunk = gw & 127;
  int basep = (b << 14) + (chunk << 7);
  const unsigned char* sp = segg + basep;
  int s0 = sp[lane];          // coalesced: seg ids of all 128 chunk pixels
  int s1 = sp[64 + lane];
  int c0 = __builtin_amdgcn_readfirstlane(s0);

  if (__all(s0 == c0 && s1 == c0)) {
    // ---- uniform chunk: 32 x 1KiB coalesced float4 loads, no atomics ----
    const float4* fq = (const float4*)(feat + ((size_t)basep << 6));
    int phase = lane >> 4, q = lane & 15;
    float4 s4 = make_float4(0.f, 0.f, 0.f, 0.f);
    float4 q4 = make_float4(0.f, 0.f, 0.f, 0.f);
#pragma unroll
    for (int i = 0; i < 32; ++i) {
      float4 v = fq[(size_t)i * 64 + (size_t)phase * 16 + q];
      s4.x += v.x; s4.y += v.y; s4.z += v.z; s4.w += v.w;
      q4.x += v.x * v.x; q4.y += v.y * v.y; q4.z += v.z * v.z; q4.w += v.w * v.w;
    }
    // reduce across the 4 pixel-phases (lanes q, q+16, q+32, q+48 share channel quad)
#pragma unroll
    for (int off = 16; off < 64; off <<= 1) {
      s4.x += __shfl_xor(s4.x, off); s4.y += __shfl_xor(s4.y, off);
      s4.z += __shfl_xor(s4.z, off); s4.w += __shfl_xor(s4.w, off);
      q4.x += __shfl_xor(q4.x, off); q4.y += __shfl_xor(q4.y, off);
      q4.z += __shfl_xor(q4.z, off); q4.w += __shfl_xor(q4.w, off);
    }
    // all lanes now hold totals for channel quad q; phase 0/1 lanes store them
    if (phase == 0) *(float4*)(psum + ((size_t)gw << 6) + (q << 2)) = s4;
    else if (phase == 1) *(float4*)(psq + ((size_t)gw << 6) + (q << 2)) = q4;
    if (lane == 0) { pseg[gw] = c0; pcnt[gw] = 128.0f; }
    return;
  }

  // ---- general chunk: pixel-serial atomic run-flush (exact for any seg pattern) ----
  if (lane == 0) pseg[gw] = -1;           // fin skips this wave's partial slot
  const float* fp = feat + ((size_t)basep << 6) + lane;
  float sacc = 0.f, qacc = 0.f, cacc = 0.f;
  int curs = c0;

  float v[32];
#pragma unroll
  for (int u = 0; u < 32; ++u) v[u] = fp[(size_t)u << 6];

#pragma unroll
  for (int kk = 0; kk < PXW; kk += 32) {
    float w[32];
    if (kk + 32 < PXW) {
#pragma unroll
      for (int u = 0; u < 32; ++u) w[u] = fp[(size_t)(kk + 32 + u) << 6];
    }
#pragma unroll
    for (int u = 0; u < 32; ++u) {
      int k = kk + u;
      int sg = __builtin_amdgcn_readlane((k & 64) ? s1 : s0, k & 63);  // SGPR broadcast
      if (sg != curs) {                                                // scalar branch
        float* a = acc + ((size_t)((b << 8) + curs) << 7);
        atomicAdd(a + lane, sacc);
        atomicAdd(a + 64 + lane, qacc);
        if (lane == 0) atomicAdd(cnt + (b << 8) + curs, cacc);
        curs = sg; sacc = 0.f; qacc = 0.f; cacc = 0.f;
      }
      sacc += v[u]; qacc += v[u] * v[u]; cacc += 1.f;
    }
#pragma unroll
    for (int u = 0; u < 32; ++u) v[u] = w[u];
  }
  {
    float* a = acc + ((size_t)((b << 8) + curs) << 7);
    atomicAdd(a + lane, sacc);
    atomicAdd(a + 64 + lane, qacc);
    if (lane == 0) atomicAdd(cnt + (b << 8) + curs, cacc);
  }
}

// ---------------- Kernel E: reduce wave-partials + atomic residue -> mean/var ----------
// Thread (bm, c): scan the 128 wave-partials of image b (pseg wave-uniform -> scalar
// compares; vector loads only on seg match), add the atomic-path accumulator, finalize.
__global__ __launch_bounds__(256) void fin_kernel(const float* __restrict__ psum,
                                                  const float* __restrict__ psq,
                                                  const int* __restrict__ pseg,
                                                  const float* __restrict__ pcnt,
                                                  const float* __restrict__ acc,
                                                  const float* __restrict__ cnt,
                                                  float* __restrict__ out) {
  int gid = blockIdx.x * 256 + threadIdx.x;     // 0..524287
  int bm = gid >> 6, c = gid & 63;              // bm = b*256+m (wave-uniform)
  int bmu = __builtin_amdgcn_readfirstlane(bm); // force SGPR indexing for scalar loads
  int b = bmu >> 8, m = bmu & 255;
  int wbase = b << 7;                            // 128 waves per image
  float s = 0.f, q = 0.f, n = 0.f;
  for (int w = 0; w < 128; ++w) {
    if (pseg[wbase + w] == m) {
      s += psum[((size_t)(wbase + w) << 6) + c];
      q += psq[((size_t)(wbase + w) << 6) + c];
      n += pcnt[wbase + w];
    }
  }
  const float* a = acc + ((size_t)bmu << 7);
  s += a[c];
  q += a[c + 64];
  n += cnt[bmu];
  float denom = fmaxf(n, 1.0f);
  float mean = s / denom;
  float var = fmaxf(q / denom - mean * mean, 0.0f);
  float* o = out + ((size_t)bmu << 7);
  o[c] = mean;
  o[c + 64] = var;
}

extern "C" void kernel_launch(void* const* d_in, const int* in_sizes, int n_in,
                              void* d_out, int out_size, void* d_ws, size_t ws_size,
                              hipStream_t stream) {
  const float* feat = (const float*)d_in[0];
  unsigned char* mask4 = (unsigned char*)d_ws;                       // 512 KB
  unsigned char* segg = mask4 + (size_t)BTN * NPIX;                  // 512 KB
  float* cnt = (float*)(segg + (size_t)BTN * NPIX);                  // 32*256*4 = 32 KB
  float* acc = cnt + (size_t)BTN * MPAR;                             // 32*256*128*4 = 4 MB
  float* psum = acc + (size_t)BTN * MPAR * 128;                      // 4096*64*4 = 1 MB
  float* psq = psum + (size_t)NWAVE * 64;                            // 1 MB
  float* pcnt = psq + (size_t)NWAVE * 64;                            // 16 KB
  int* pseg = (int*)(pcnt + NWAVE);                                  // 16 KB
  float* out = (float*)d_out;                                        // mean|var

  edge_kernel<<<BTN * 64, 256, 0, stream>>>(feat, mask4, (float4*)acc, (float4*)cnt);
  prop_kernel<<<BTN, 1024, 0, stream>>>(mask4, segg);
  agg_kernel<<<NWAVE / 4, 256, 0, stream>>>(feat, segg, acc, cnt, psum, psq, pseg, pcnt);
  fin_kernel<<<BTN * MPAR * CCH / 256, 256, 0, stream>>>(psum, psq, pseg, pcnt, acc, cnt, out);
}

// Round 7
// 239.442 us; speedup vs baseline: 1.0776x; 1.0776x over previous
//
#include <hip/hip_runtime.h>
#include <stdint.h>

#define HH 128
#define WW 128
#define NPIX 16384
#define BTN 32
#define CCH 64
#define MPAR 256
#define SENT 16384
#define NSTEPS 40

// ---------------- Kernel A': fused edge-mask + per-row sum/sq partials ----------------
// One wave per image row (lane = channel). Streams each 256-B pixel record exactly once,
// fully sequentially (32 KB contiguous per wave) -> full-line HBM efficiency, replacing
// the old edge(half-line strided) + agg(other-half strided) double pass.
// While streaming, ch0-7 are staged to LDS for the mask math (bit0 E, bit1 SW, bit2 S,
// bit3 SE; edge iff dist^2 + 1e-12 < 1, same monotone-transform trick + rare exact
// finish over ch8-63). Row partials (sum[64]|sq[64]) stored to prow — seg-independent.
__global__ __launch_bounds__(256) void fused_kernel(const float* __restrict__ feat,
                                                    unsigned char* __restrict__ mask4,
                                                    float* __restrict__ prow) {
  __shared__ float lm[5][128][9];         // [tile row(+halo)][x][ch0..7], pad 9: ~23 KB
  int blk = blockIdx.x;                   // 1024 = 32 images * 32 row-quads
  int tid = threadIdx.x;
  int lane = tid & 63, w = tid >> 6;
  int b = blk >> 5;
  int ty = (blk & 31) << 2;               // first row of this block's 4-row tile
  int y = ty + w;                         // this wave's row

  const float* fr = feat + (((size_t)(b << 14) + (y << 7)) << 6);
  float sacc = 0.f, qacc = 0.f;
  for (int p0 = 0; p0 < 128; p0 += 8) {
    float t[8];
#pragma unroll
    for (int u = 0; u < 8; ++u) t[u] = fr[((p0 + u) << 6) + lane];   // 256 B/instr, seq.
#pragma unroll
    for (int u = 0; u < 8; ++u) { sacc += t[u]; qacc += t[u] * t[u]; }
    if (lane < 8) {
#pragma unroll
      for (int u = 0; u < 8; ++u) lm[w][p0 + u][lane] = t[u];
    }
  }
  // halo row ty+4 (ch0-7 only) for the last row's S/SW/SE neighbors
  {
    int px = tid >> 1, h = tid & 1;
    int hy = ty + 4;
    float4 v;
    if (hy < HH)
      v = *(const float4*)(feat + (((size_t)(b << 14) + (hy << 7) + px) << 6) + h * 4);
    else
      v = make_float4(1e6f, 1e6f, 1e6f, 1e6f);
    lm[4][px][h * 4 + 0] = v.x; lm[4][px][h * 4 + 1] = v.y;
    lm[4][px][h * 4 + 2] = v.z; lm[4][px][h * 4 + 3] = v.w;
  }
  // row partials: lane = channel, direct store, no cross-lane ops
  float* pr = prow + (((size_t)(b << 7) + y) << 7);
  pr[lane] = sacc;
  pr[64 + lane] = qacc;
  __syncthreads();

  // masks: 512 pixels / 256 threads = 2 each
#pragma unroll
  for (int i = 0; i < 2; ++i) {
    int p = tid + (i << 8);
    int row = p >> 7, x = p & 127;
    int gy = ty + row;
    int xm = (x > 0) ? x - 1 : 0;
    int xp = (x < 127) ? x + 1 : 127;
    float a0 = 0.f, a1 = 0.f, a2 = 0.f, a3 = 0.f;
#pragma unroll
    for (int c = 0; c < 8; ++c) {
      float o = lm[row][x][c];
      float d0 = o - lm[row][xp][c];        // E
      float d1 = o - lm[row + 1][xm][c];    // SW
      float d2 = o - lm[row + 1][x][c];     // S
      float d3 = o - lm[row + 1][xp][c];    // SE
      a0 += d0 * d0; a1 += d1 * d1; a2 += d2 * d2; a3 += d3 * d3;
    }
    bool vS = (gy + 1) < HH;
    float acc[4] = {a0, a1, a2, a3};
    bool val[4] = {x < 127, vS && x > 0, vS, vS && x < 127};
    const int offp[4] = {1, 127, 128, 129};
    const float* fp = feat + (((size_t)(b << 14) + (gy << 7) + x) << 6);
    unsigned m = 0;
#pragma unroll
    for (int j = 0; j < 4; ++j) {
      if (val[j]) {
        float s = acc[j];
        if (s < 1.0f) {                    // rare: finish channels 8..63 exactly
          const float* np_ = fp + ((size_t)offp[j] << 6);
          for (int c = 8; c < 64; ++c) {
            float d = fp[c] - np_[c];
            s += d * d;
          }
        }
        if (s + 1e-12f < 1.0f) m |= (1u << j);
      }
    }
    mask4[(b << 14) + (gy << 7) + x] = (unsigned char)m;
  }
}

// ---------------- Kernel B: propagation + relabel (unchanged from R2) ----------------
// e8 bits: b0 NW, b1 N, b2 NE, b3 W, b4 E, b5 SW, b6 S, b7 SE
// Fast path: zero edges image-wide -> seg[p] = min(p,255) closed form (exact).
__global__ __launch_bounds__(1024) void prop_kernel(const unsigned char* __restrict__ mask4g,
                                                    unsigned char* __restrict__ segg) {
  __shared__ __align__(16) unsigned short lab[NPIX];   // 32 KB
  __shared__ __align__(16) unsigned char e8[NPIX];     // 16 KB
  __shared__ __align__(16) unsigned short rnk[NPIX];   // 32 KB
  __shared__ int flags[2];
  __shared__ int wsum[16];
  __shared__ int wexc[16];
  __shared__ int wany[16];
  int b = blockIdx.x;
  int tid = threadIdx.x;
  int lane = tid & 63, wid = tid >> 6;

  uint4 mv = ((const uint4*)(mask4g + ((size_t)b << 14)))[tid];
  ((uint4*)e8)[tid] = mv;
  unsigned anyv = mv.x | mv.y | mv.z | mv.w;
  unsigned long long bal = __ballot(anyv != 0);
  if (lane == 0) wany[wid] = (bal != 0ull) ? 1 : 0;
  __syncthreads();

  int tot = 0;
#pragma unroll
  for (int i = 0; i < 16; ++i) tot |= wany[i];
  if (tot == 0) {
    uint4 w;
    if (tid < 16) {
      unsigned b0 = (unsigned)(tid * 16);
      w.x = b0 | ((b0 + 1) << 8) | ((b0 + 2) << 16) | ((b0 + 3) << 24);
      w.y = (b0 + 4) | ((b0 + 5) << 8) | ((b0 + 6) << 16) | ((b0 + 7) << 24);
      w.z = (b0 + 8) | ((b0 + 9) << 8) | ((b0 + 10) << 16) | ((b0 + 11) << 24);
      w.w = (b0 + 12) | ((b0 + 13) << 8) | ((b0 + 14) << 16) | ((b0 + 15) << 24);
    } else {
      w = make_uint4(~0u, ~0u, ~0u, ~0u);
    }
    ((uint4*)(segg + ((size_t)b << 14)))[tid] = w;
    return;
  }

  unsigned char tmp[16];
  {
    int base = tid * 16;
#pragma unroll
    for (int i = 0; i < 16; ++i) {
      int p = base + i;
      int y = p >> 7, x = p & (WW - 1);
      unsigned own = e8[p];
      unsigned nw = (y > 0 && x > 0) ? e8[p - 129] : 0;
      unsigned n_ = (y > 0) ? e8[p - 128] : 0;
      unsigned ne = (y > 0 && x < WW - 1) ? e8[p - 127] : 0;
      unsigned w_ = (x > 0) ? e8[p - 1] : 0;
      unsigned v = ((nw >> 3) & 1) | (((n_ >> 2) & 1) << 1) | (((ne >> 1) & 1) << 2) |
                   ((w_ & 1) << 3) | ((own & 1) << 4) | (((own >> 1) & 1) << 5) |
                   (((own >> 2) & 1) << 6) | (((own >> 3) & 1) << 7);
      tmp[i] = (unsigned char)v;
    }
  }
  __syncthreads();
  {
    int base = tid * 16;
#pragma unroll
    for (int i = 0; i < 16; ++i) e8[base + i] = tmp[i];
#pragma unroll
    for (int i = 0; i < 16; ++i) lab[base + i] = (unsigned short)(base + i);
  }
  if (tid == 0) { flags[0] = 0; flags[1] = 0; }
  __syncthreads();

  int x0 = (tid & 31) * 4, y0 = (tid >> 5) * 4;
  int cur[4][4], eb[4][4];
#pragma unroll
  for (int r = 0; r < 4; ++r)
#pragma unroll
    for (int c = 0; c < 4; ++c) {
      cur[r][c] = (y0 + r) * WW + x0 + c;
      eb[r][c] = e8[(y0 + r) * WW + x0 + c];
    }

  for (int it = 0; it < NSTEPS; ++it) {
    int top[6], bot[6], lft[4], rgt[4];
#pragma unroll
    for (int c = 0; c < 6; ++c) {
      top[c] = lab[(((y0 - 1) * WW) + x0 - 1 + c) & (NPIX - 1)];
      bot[c] = lab[(((y0 + 4) * WW) + x0 - 1 + c) & (NPIX - 1)];
    }
#pragma unroll
    for (int r = 0; r < 4; ++r) {
      lft[r] = lab[(((y0 + r) * WW) + x0 - 1) & (NPIX - 1)];
      rgt[r] = lab[(((y0 + r) * WW) + x0 + 4) & (NPIX - 1)];
    }
    int nl[4][4];
    bool ch = false;
#pragma unroll
    for (int r = 0; r < 4; ++r) {
#pragma unroll
      for (int c = 0; c < 4; ++c) {
        int m = cur[r][c];
        int e = eb[r][c];
        int v;
        v = (r > 0) ? ((c > 0) ? cur[r - 1][c - 1] : lft[r - 1]) : top[c];        // NW
        m = min(m, (e & 1) ? v : SENT);
        v = (r > 0) ? cur[r - 1][c] : top[c + 1];                                 // N
        m = min(m, (e & 2) ? v : SENT);
        v = (r > 0) ? ((c < 3) ? cur[r - 1][c + 1] : rgt[r - 1]) : top[c + 2];    // NE
        m = min(m, (e & 4) ? v : SENT);
        v = (c > 0) ? cur[r][c - 1] : lft[r];                                     // W
        m = min(m, (e & 8) ? v : SENT);
        v = (c < 3) ? cur[r][c + 1] : rgt[r];                                     // E
        m = min(m, (e & 16) ? v : SENT);
        v = (r < 3) ? ((c > 0) ? cur[r + 1][c - 1] : lft[r + 1]) : bot[c];        // SW
        m = min(m, (e & 32) ? v : SENT);
        v = (r < 3) ? cur[r + 1][c] : bot[c + 1];                                 // S
        m = min(m, (e & 64) ? v : SENT);
        v = (r < 3) ? ((c < 3) ? cur[r + 1][c + 1] : rgt[r + 1]) : bot[c + 2];    // SE
        m = min(m, (e & 128) ? v : SENT);
        nl[r][c] = m;
        ch |= (m != cur[r][c]);
      }
    }
    __syncthreads();
#pragma unroll
    for (int r = 0; r < 4; ++r) {
      unsigned lo = (unsigned)nl[r][0] | ((unsigned)nl[r][1] << 16);
      unsigned hi = (unsigned)nl[r][2] | ((unsigned)nl[r][3] << 16);
      *((uint2*)&lab[(y0 + r) * WW + x0]) = make_uint2(lo, hi);
    }
    if (ch) flags[it & 1] = 1;
    if (tid == 0) flags[(it + 1) & 1] = 0;
#pragma unroll
    for (int r = 0; r < 4; ++r)
#pragma unroll
      for (int c = 0; c < 4; ++c) cur[r][c] = nl[r][c];
    __syncthreads();
    if (!flags[it & 1]) break;
  }

  __syncthreads();
  ((uint4*)e8)[tid] = make_uint4(0u, 0u, 0u, 0u);
  __syncthreads();
#pragma unroll
  for (int i = 0; i < 16; ++i) {
    int p = tid + i * 1024;
    e8[lab[p]] = 1;
  }
  __syncthreads();
  int pres[16];
  int base = tid * 16;
#pragma unroll
  for (int i = 0; i < 16; ++i) pres[i] = e8[base + i];
  int s_local = 0;
#pragma unroll
  for (int i = 0; i < 16; ++i) s_local += pres[i];
  int inc = s_local;
#pragma unroll
  for (int off = 1; off < 64; off <<= 1) {
    int v = __shfl_up(inc, off, 64);
    if (lane >= off) inc += v;
  }
  if (lane == 63) wsum[wid] = inc;
  __syncthreads();
  if (wid == 0) {
    int tt = (lane < 16) ? wsum[lane] : 0;
    int winc = tt;
#pragma unroll
    for (int off = 1; off < 16; off <<= 1) {
      int v = __shfl_up(winc, off, 64);
      if (lane >= off) winc += v;
    }
    if (lane < 16) wexc[lane] = winc - tt;
  }
  __syncthreads();
  int run = wexc[wid] + (inc - s_local);
#pragma unroll
  for (int i = 0; i < 16; ++i) {
    run += pres[i];
    rnk[base + i] = (unsigned short)(run - 1);
  }
  __syncthreads();
  unsigned char* so = segg + ((size_t)b << 14);
#pragma unroll
  for (int i = 0; i < 16; ++i) {
    int p = tid + i * 1024;
    int sg = rnk[lab[p]];
    so[p] = (unsigned char)min(sg, 255);
  }
}

// ---------------- Kernel C: LDS-resident per-image aggregation + finalize ----------------
// One block per image. Rows whose seg is uniform (the common case: chunk==row) consume
// the precomputed prow partials; mixed rows are handled per-pixel exactly (L3-hot feat).
// acc[256][128] lives in LDS; thread c owns column c -> no races, no atomics anywhere.
__global__ __launch_bounds__(256) void fin_kernel(const float* __restrict__ feat,
                                                  const unsigned char* __restrict__ segg,
                                                  const float* __restrict__ prow,
                                                  float* __restrict__ out) {
  __shared__ __align__(16) float accL[MPAR][128];      // 128 KB
  __shared__ __align__(16) unsigned char segL[NPIX];   // 16 KB
  __shared__ float cntL[MPAR];
  __shared__ short rowseg[128];
  int b = blockIdx.x;
  int tid = threadIdx.x;

  for (int i = tid; i < MPAR * 32; i += 256) ((float4*)accL)[i] = make_float4(0.f, 0.f, 0.f, 0.f);
  cntL[tid] = 0.f;
  for (int i = 0; i < 16; ++i)
    ((unsigned int*)segL)[tid + (i << 8)] = ((const unsigned int*)(segg + ((size_t)b << 14)))[tid + (i << 8)];
  __syncthreads();

  if (tid < 128) {   // row-uniformity classification
    const unsigned int* rp = (const unsigned int*)(segL + (tid << 7));
    unsigned int u0 = rp[0];
    unsigned int sp = (u0 & 255u) * 0x01010101u;
    bool ok = true;
#pragma unroll
    for (int j = 0; j < 32; ++j) ok &= (rp[j] == sp);
    rowseg[tid] = ok ? (short)(u0 & 255u) : (short)-1;
  }
  __syncthreads();

  if (tid < 128) {   // c = tid: columns 0..63 sum, 64..127 sq
    // uniform rows: run-length accumulate prow partials into LDS
    int curs = -1;
    float racc = 0.f;
    for (int r = 0; r < 128; ++r) {
      float v = prow[(((size_t)(b << 7) + r) << 7) + tid];   // coalesced 512 B / row
      int s = rowseg[r];
      if (s != curs) {
        if (curs >= 0) accL[curs][tid] += racc;
        curs = s; racc = 0.f;
      }
      if (s >= 0) racc += v;
    }
    if (curs >= 0) accL[curs][tid] += racc;
    // mixed rows: exact per-pixel (rare)
    int ch = tid & 63;
    bool issq = tid >= 64;
    for (int r = 0; r < 128; ++r)
      if (rowseg[r] < 0) {
        const float* fb = feat + (((size_t)(b << 14) + (r << 7)) << 6);
        for (int p = 0; p < 128; ++p) {
          int s = segL[(r << 7) + p];
          float v = fb[(p << 6) + ch];
          accL[s][tid] += issq ? v * v : v;
        }
      }
  } else if (tid == 128) {   // counts, run-length over rows
    int curs = -1;
    float rc = 0.f;
    for (int r = 0; r < 128; ++r) {
      int s = rowseg[r];
      if (s != curs) {
        if (curs >= 0) cntL[curs] += rc;
        curs = s; rc = 0.f;
      }
      if (s >= 0) rc += 128.f;
    }
    if (curs >= 0) cntL[curs] += rc;
    for (int r = 0; r < 128; ++r)
      if (rowseg[r] < 0)
        for (int p = 0; p < 128; ++p) cntL[segL[(r << 7) + p]] += 1.f;
  }
  __syncthreads();

  for (int i = 0; i < 64; ++i) {   // 256 segs x 64 ch / 256 threads
    int idx = tid + (i << 8);
    int m = idx >> 6, ch = idx & 63;
    float n = cntL[m];
    float s = accL[m][ch], q = accL[m][ch + 64];
    float denom = fmaxf(n, 1.0f);
    float mean = s / denom;
    float var = fmaxf(q / denom - mean * mean, 0.0f);
    float* o = out + (((size_t)(b << 8) + m) << 7);
    o[ch] = mean;
    o[64 + ch] = var;
  }
}

extern "C" void kernel_launch(void* const* d_in, const int* in_sizes, int n_in,
                              void* d_out, int out_size, void* d_ws, size_t ws_size,
                              hipStream_t stream) {
  const float* feat = (const float*)d_in[0];
  unsigned char* mask4 = (unsigned char*)d_ws;                       // 512 KB (fully written)
  unsigned char* segg = mask4 + (size_t)BTN * NPIX;                  // 512 KB (fully written)
  float* prow = (float*)(segg + (size_t)BTN * NPIX);                 // 4096*128*4 = 2 MB
  float* out = (float*)d_out;                                        // mean|var (fully written)

  fused_kernel<<<BTN * 32, 256, 0, stream>>>(feat, mask4, prow);
  prop_kernel<<<BTN, 1024, 0, stream>>>(mask4, segg);
  fin_kernel<<<BTN, 256, 0, stream>>>(feat, segg, prow, out);
}

// Round 8
// 215.417 us; speedup vs baseline: 1.1978x; 1.1115x over previous
//
#include <hip/hip_runtime.h>
#include <stdint.h>

#define HH 128
#define WW 128
#define NPIX 16384
#define BTN 32
#define CCH 64
#define MPAR 256
#define SENT 16384
#define NSTEPS 40

// ---------------- Kernel A: 4-direction edge masks (LDS-tiled, early-out) ----------------
// bit0 E(0,1), bit1 SW(1,-1), bit2 S(1,0), bit3 SE(1,1)
// Edge condition: aff>0.5 <=> dist<1 <=> s+1e-12 < 1 (monotone transforms; no sqrt/div).
// Also zeroes acc (d_out) and cnt for the downstream atomic aggregation (saves 2 dispatches).
#define ETX 32
#define ETY 8
__global__ __launch_bounds__(256) void edge_kernel(const float* __restrict__ feat,
                                                   unsigned char* __restrict__ mask4,
                                                   float4* __restrict__ accz,
                                                   float4* __restrict__ cntz) {
  __shared__ float lds[8][308];           // [channel][staged pixel], 306 used
  int blk = blockIdx.x;                   // 2048 blocks
  int tid = threadIdx.x;

  // zero acc: 262144 float4 over 2048 blocks = 128/block; cnt: 2048 float4 = 1/block
  if (tid < 128) accz[blk * 128 + tid] = make_float4(0.f, 0.f, 0.f, 0.f);
  else if (tid == 128) cntz[blk] = make_float4(0.f, 0.f, 0.f, 0.f);

  int b = blk >> 6;
  int t = blk & 63;                       // 16 tile-rows x 4 tile-cols
  int ty0 = (t >> 2) * ETY;
  int tx0 = (t & 3) * ETX;
  const float* fb = feat + ((size_t)b << 20);   // b * 16384 * 64

  for (int sp = tid; sp < 306; sp += 256) {
    int gy = ty0 + sp / 34;
    int gx = tx0 - 1 + sp % 34;
    if (gy < HH && (unsigned)gx < (unsigned)WW) {
      const float* pp = fb + (((size_t)(gy << 7) + gx) << 6);
      float4 v0 = *(const float4*)pp;
      float4 v1 = *(const float4*)(pp + 4);
      lds[0][sp] = v0.x; lds[1][sp] = v0.y; lds[2][sp] = v0.z; lds[3][sp] = v0.w;
      lds[4][sp] = v1.x; lds[5][sp] = v1.y; lds[6][sp] = v1.z; lds[7][sp] = v1.w;
    } else {
#pragma unroll
      for (int c = 0; c < 8; ++c) lds[c][sp] = 1e6f;
    }
  }
  __syncthreads();

  int tx = tid & 31, ty = tid >> 5;
  int idx = ty * 34 + tx + 1;
  int gx = tx0 + tx, gy = ty0 + ty;

  float own[8];
#pragma unroll
  for (int c = 0; c < 8; ++c) own[c] = lds[c][idx];
  float a0 = 0.f, a1 = 0.f, a2 = 0.f, a3 = 0.f;
#pragma unroll
  for (int c = 0; c < 8; ++c) {
    float o = own[c];
    float d0 = o - lds[c][idx + 1];     // E
    float d1 = o - lds[c][idx + 33];    // SW
    float d2 = o - lds[c][idx + 34];    // S
    float d3 = o - lds[c][idx + 35];    // SE
    a0 += d0 * d0; a1 += d1 * d1; a2 += d2 * d2; a3 += d3 * d3;
  }

  bool vS = (gy + 1) < HH;
  float acc[4] = {a0, a1, a2, a3};
  bool val[4] = {(gx + 1) < WW, vS && gx >= 1, vS, vS && (gx + 1) < WW};
  const int offp[4] = {1, 127, 128, 129};
  const float* fp = fb + (((size_t)(gy << 7) + gx) << 6);
  unsigned m = 0;
#pragma unroll
  for (int j = 0; j < 4; ++j) {
    if (val[j]) {
      float s = acc[j];
      if (s < 1.0f) {                    // rare: finish channels 8..63 exactly
        const float* np_ = fp + ((size_t)offp[j] << 6);
        for (int c = 8; c < 64; ++c) {
          float d = fp[c] - np_[c];
          s += d * d;
        }
      }
      if (s + 1e-12f < 1.0f) m |= (1u << j);
    }
  }
  mask4[(b << 14) + (gy << 7) + gx] = (unsigned char)m;
}

// ---------------- Kernel B: propagation + relabel ----------------
// e8 bits: b0 NW, b1 N, b2 NE, b3 W, b4 E, b5 SW, b6 S, b7 SE
// Fast path: if the image has NO edges at all (image-wide OR of mask4 == 0), the exact
// result of propagate+relabel is seg[p] = min(p, 255) (identity labels, all present,
// rank = identity). Full path kept as the general-case fallback (exact for any input).
__global__ __launch_bounds__(1024) void prop_kernel(const unsigned char* __restrict__ mask4g,
                                                    unsigned char* __restrict__ segg) {
  __shared__ __align__(16) unsigned short lab[NPIX];   // 32 KB
  __shared__ __align__(16) unsigned char e8[NPIX];     // 16 KB
  __shared__ __align__(16) unsigned short rnk[NPIX];   // 32 KB
  __shared__ int flags[2];
  __shared__ int wsum[16];
  __shared__ int wexc[16];
  __shared__ int wany[16];
  int b = blockIdx.x;
  int tid = threadIdx.x;
  int lane = tid & 63, wid = tid >> 6;

  uint4 mv = ((const uint4*)(mask4g + ((size_t)b << 14)))[tid];
  ((uint4*)e8)[tid] = mv;
  unsigned anyv = mv.x | mv.y | mv.z | mv.w;
  unsigned long long bal = __ballot(anyv != 0);
  if (lane == 0) wany[wid] = (bal != 0ull) ? 1 : 0;
  __syncthreads();

  int tot = 0;
#pragma unroll
  for (int i = 0; i < 16; ++i) tot |= wany[i];   // LDS broadcast reads
  if (tot == 0) {
    // zero-edge closed form: seg[p] = min(p, 255); 16 coalesced bytes per thread
    uint4 w;
    if (tid < 16) {
      unsigned b0 = (unsigned)(tid * 16);
      w.x = b0 | ((b0 + 1) << 8) | ((b0 + 2) << 16) | ((b0 + 3) << 24);
      w.y = (b0 + 4) | ((b0 + 5) << 8) | ((b0 + 6) << 16) | ((b0 + 7) << 24);
      w.z = (b0 + 8) | ((b0 + 9) << 8) | ((b0 + 10) << 16) | ((b0 + 11) << 24);
      w.w = (b0 + 12) | ((b0 + 13) << 8) | ((b0 + 14) << 16) | ((b0 + 15) << 24);
    } else {
      w = make_uint4(~0u, ~0u, ~0u, ~0u);
    }
    ((uint4*)(segg + ((size_t)b << 14)))[tid] = w;
    return;
  }

  unsigned char tmp[16];
  {
    int base = tid * 16;
#pragma unroll
    for (int i = 0; i < 16; ++i) {
      int p = base + i;
      int y = p >> 7, x = p & (WW - 1);
      unsigned own = e8[p];
      unsigned nw = (y > 0 && x > 0) ? e8[p - 129] : 0;
      unsigned n_ = (y > 0) ? e8[p - 128] : 0;
      unsigned ne = (y > 0 && x < WW - 1) ? e8[p - 127] : 0;
      unsigned w_ = (x > 0) ? e8[p - 1] : 0;
      unsigned v = ((nw >> 3) & 1) | (((n_ >> 2) & 1) << 1) | (((ne >> 1) & 1) << 2) |
                   ((w_ & 1) << 3) | ((own & 1) << 4) | (((own >> 1) & 1) << 5) |
                   (((own >> 2) & 1) << 6) | (((own >> 3) & 1) << 7);
      tmp[i] = (unsigned char)v;
    }
  }
  __syncthreads();
  {
    int base = tid * 16;
#pragma unroll
    for (int i = 0; i < 16; ++i) e8[base + i] = tmp[i];
#pragma unroll
    for (int i = 0; i < 16; ++i) lab[base + i] = (unsigned short)(base + i);
  }
  if (tid == 0) { flags[0] = 0; flags[1] = 0; }
  __syncthreads();

  int x0 = (tid & 31) * 4, y0 = (tid >> 5) * 4;
  int cur[4][4], eb[4][4];
#pragma unroll
  for (int r = 0; r < 4; ++r)
#pragma unroll
    for (int c = 0; c < 4; ++c) {
      cur[r][c] = (y0 + r) * WW + x0 + c;
      eb[r][c] = e8[(y0 + r) * WW + x0 + c];
    }

  for (int it = 0; it < NSTEPS; ++it) {
    int top[6], bot[6], lft[4], rgt[4];
#pragma unroll
    for (int c = 0; c < 6; ++c) {
      top[c] = lab[(((y0 - 1) * WW) + x0 - 1 + c) & (NPIX - 1)];
      bot[c] = lab[(((y0 + 4) * WW) + x0 - 1 + c) & (NPIX - 1)];
    }
#pragma unroll
    for (int r = 0; r < 4; ++r) {
      lft[r] = lab[(((y0 + r) * WW) + x0 - 1) & (NPIX - 1)];
      rgt[r] = lab[(((y0 + r) * WW) + x0 + 4) & (NPIX - 1)];
    }
    int nl[4][4];
    bool ch = false;
#pragma unroll
    for (int r = 0; r < 4; ++r) {
#pragma unroll
      for (int c = 0; c < 4; ++c) {
        int m = cur[r][c];
        int e = eb[r][c];
        int v;
        v = (r > 0) ? ((c > 0) ? cur[r - 1][c - 1] : lft[r - 1]) : top[c];        // NW
        m = min(m, (e & 1) ? v : SENT);
        v = (r > 0) ? cur[r - 1][c] : top[c + 1];                                 // N
        m = min(m, (e & 2) ? v : SENT);
        v = (r > 0) ? ((c < 3) ? cur[r - 1][c + 1] : rgt[r - 1]) : top[c + 2];    // NE
        m = min(m, (e & 4) ? v : SENT);
        v = (c > 0) ? cur[r][c - 1] : lft[r];                                     // W
        m = min(m, (e & 8) ? v : SENT);
        v = (c < 3) ? cur[r][c + 1] : rgt[r];                                     // E
        m = min(m, (e & 16) ? v : SENT);
        v = (r < 3) ? ((c > 0) ? cur[r + 1][c - 1] : lft[r + 1]) : bot[c];        // SW
        m = min(m, (e & 32) ? v : SENT);
        v = (r < 3) ? cur[r + 1][c] : bot[c + 1];                                 // S
        m = min(m, (e & 64) ? v : SENT);
        v = (r < 3) ? ((c < 3) ? cur[r + 1][c + 1] : rgt[r + 1]) : bot[c + 2];    // SE
        m = min(m, (e & 128) ? v : SENT);
        nl[r][c] = m;
        ch |= (m != cur[r][c]);
      }
    }
    __syncthreads();
#pragma unroll
    for (int r = 0; r < 4; ++r) {
      unsigned lo = (unsigned)nl[r][0] | ((unsigned)nl[r][1] << 16);
      unsigned hi = (unsigned)nl[r][2] | ((unsigned)nl[r][3] << 16);
      *((uint2*)&lab[(y0 + r) * WW + x0]) = make_uint2(lo, hi);
    }
    if (ch) flags[it & 1] = 1;
    if (tid == 0) flags[(it + 1) & 1] = 0;
#pragma unroll
    for (int r = 0; r < 4; ++r)
#pragma unroll
      for (int c = 0; c < 4; ++c) cur[r][c] = nl[r][c];
    __syncthreads();
    if (!flags[it & 1]) break;   // converged: remaining iterations are identity (exact)
  }

  __syncthreads();
  ((uint4*)e8)[tid] = make_uint4(0u, 0u, 0u, 0u);
  __syncthreads();
#pragma unroll
  for (int i = 0; i < 16; ++i) {
    int p = tid + i * 1024;
    e8[lab[p]] = 1;
  }
  __syncthreads();
  int pres[16];
  int base = tid * 16;
#pragma unroll
  for (int i = 0; i < 16; ++i) pres[i] = e8[base + i];
  int s_local = 0;
#pragma unroll
  for (int i = 0; i < 16; ++i) s_local += pres[i];
  int inc = s_local;
#pragma unroll
  for (int off = 1; off < 64; off <<= 1) {
    int v = __shfl_up(inc, off, 64);
    if (lane >= off) inc += v;
  }
  if (lane == 63) wsum[wid] = inc;
  __syncthreads();
  if (wid == 0) {
    int tt = (lane < 16) ? wsum[lane] : 0;
    int winc = tt;
#pragma unroll
    for (int off = 1; off < 16; off <<= 1) {
      int v = __shfl_up(winc, off, 64);
      if (lane >= off) winc += v;
    }
    if (lane < 16) wexc[lane] = winc - tt;
  }
  __syncthreads();
  int run = wexc[wid] + (inc - s_local);
#pragma unroll
  for (int i = 0; i < 16; ++i) {
    run += pres[i];
    rnk[base + i] = (unsigned short)(run - 1);
  }
  __syncthreads();
  unsigned char* so = segg + ((size_t)b << 14);
#pragma unroll
  for (int i = 0; i < 16; ++i) {
    int p = tid + i * 1024;
    int sg = rnk[lab[p]];
    so[p] = (unsigned char)min(sg, 255);
  }
}

// ---------------- Kernel D: aggregation (run-adaptive) ----------------
// Diagnosis (R2..R7): kernel time = critical-path tail of the ~2 high-run chunks per
// image (e.g. 128 single-pixel segments in rows 0-1), whose serial run-flush chain
// costs 128 x ~350ns. Fix: count runs via ballot; nruns<=8 -> original serial
// run-flush (optimal for uniform chunks); nruns>8 -> per-pixel INDEPENDENT atomics
// (no curs dependency chain, fire-and-forget, latency-hidden; distinct segments ->
// no same-line contention). Both paths exact for any seg pattern.
#define PXW 128
__global__ __launch_bounds__(256) void agg_kernel(const float* __restrict__ feat,
                                                  const unsigned char* __restrict__ segg,
                                                  float* __restrict__ acc,
                                                  float* __restrict__ cnt) {
  int lane = threadIdx.x & 63;
  int gw = blockIdx.x * 4 + (threadIdx.x >> 6);
  int b = gw >> 7;            // 128 waves per image
  int chunk = gw & 127;
  int basep = (b << 14) + (chunk << 7);
  const unsigned char* sp = segg + basep;
  int s0 = sp[lane];          // coalesced: seg ids of all 128 chunk pixels
  int s1 = sp[64 + lane];
  const float* fp = feat + ((size_t)basep << 6) + lane;

  // run count across the 128-pixel chunk (2 ballots)
  int p0 = __shfl_up(s0, 1, 64);
  int p1 = __shfl_up(s1, 1, 64);
  int last0 = __builtin_amdgcn_readlane(s0, 63);
  unsigned long long m0 = __ballot(lane > 0 && s0 != p0);
  unsigned long long m1 = __ballot(s1 != ((lane == 0) ? last0 : p1));
  int nruns = 1 + __popcll(m0) + __popcll(m1);

  if (nruns > 8) {
    // ---- high-run chunk: per-pixel independent atomics, no serial chain ----
    for (int kk = 0; kk < PXW; kk += 32) {
      float v[32];
#pragma unroll
      for (int u = 0; u < 32; ++u) v[u] = fp[(size_t)(kk + u) << 6];
#pragma unroll
      for (int u = 0; u < 32; ++u) {
        int k = kk + u;
        int sg = __builtin_amdgcn_readlane((k & 64) ? s1 : s0, k & 63);
        float* a = acc + ((size_t)((b << 8) + sg) << 7);
        atomicAdd(a + lane, v[u]);
        atomicAdd(a + 64 + lane, v[u] * v[u]);
        if (lane == 0) atomicAdd(cnt + (b << 8) + sg, 1.0f);
      }
    }
    return;
  }

  // ---- low-run chunk: pixel-serial run flushing (exact, few flushes) ----
  float sacc = 0.f, qacc = 0.f, cacc = 0.f;
  int curs = __builtin_amdgcn_readlane(s0, 0);

  float v[32];
#pragma unroll
  for (int u = 0; u < 32; ++u) v[u] = fp[(size_t)u << 6];

#pragma unroll
  for (int kk = 0; kk < PXW; kk += 32) {
    float w[32];
    if (kk + 32 < PXW) {
#pragma unroll
      for (int u = 0; u < 32; ++u) w[u] = fp[(size_t)(kk + 32 + u) << 6];
    }
#pragma unroll
    for (int u = 0; u < 32; ++u) {
      int k = kk + u;
      int sg = __builtin_amdgcn_readlane((k & 64) ? s1 : s0, k & 63);  // SGPR broadcast
      if (sg != curs) {                                                // scalar branch
        float* a = acc + ((size_t)((b << 8) + curs) << 7);
        atomicAdd(a + lane, sacc);
        atomicAdd(a + 64 + lane, qacc);
        if (lane == 0) atomicAdd(cnt + (b << 8) + curs, cacc);
        curs = sg; sacc = 0.f; qacc = 0.f; cacc = 0.f;
      }
      sacc += v[u]; qacc += v[u] * v[u]; cacc += 1.f;
    }
#pragma unroll
    for (int u = 0; u < 32; ++u) v[u] = w[u];
  }
  {
    float* a = acc + ((size_t)((b << 8) + curs) << 7);
    atomicAdd(a + lane, sacc);
    atomicAdd(a + 64 + lane, qacc);
    if (lane == 0) atomicAdd(cnt + (b << 8) + curs, cacc);
  }
}

// ---------------- Kernel E: finalize mean/var in place ----------------
__global__ __launch_bounds__(256) void fin_kernel(float* __restrict__ acc,
                                                  const float* __restrict__ cnt) {
  int gid = blockIdx.x * 256 + threadIdx.x;   // 0..524287
  int bm = gid >> 6, c = gid & 63;
  float* a = acc + ((size_t)bm << 7);
  float s = a[c], q = a[c + 64];
  float n = cnt[bm];
  float denom = fmaxf(n, 1.0f);
  float mean = s / denom;
  float var = fmaxf(q / denom - mean * mean, 0.0f);
  a[c] = mean;
  a[c + 64] = var;
}

extern "C" void kernel_launch(void* const* d_in, const int* in_sizes, int n_in,
                              void* d_out, int out_size, void* d_ws, size_t ws_size,
                              hipStream_t stream) {
  const float* feat = (const float*)d_in[0];
  unsigned char* mask4 = (unsigned char*)d_ws;                       // 512 KB
  unsigned char* segg = mask4 + (size_t)BTN * NPIX;                  // 512 KB
  float* cnt = (float*)(segg + (size_t)BTN * NPIX);                  // 32 KB
  float* acc = (float*)d_out;                                       // sums|sqs -> mean|var

  edge_kernel<<<BTN * 64, 256, 0, stream>>>(feat, mask4, (float4*)acc, (float4*)cnt);
  prop_kernel<<<BTN, 1024, 0, stream>>>(mask4, segg);
  agg_kernel<<<BTN * NPIX / PXW / 4, 256, 0, stream>>>(feat, segg, acc, cnt);
  fin_kernel<<<BTN * MPAR * CCH / 256, 256, 0, stream>>>(acc, cnt);
}